// Round 1
// baseline (96.537 us; speedup 1.0000x reference)
//
#include <hip/hip_runtime.h>

#define N_TEX 65536
#define C 16
#define U 4194304

// Each sample point u produces 16 floats (4 float4s). We assign 4 consecutive
// lanes to one sample: lane handles one float4 of channels. This makes output
// stores perfectly coalesced (64 consecutive lanes -> 1 KiB contiguous).
__global__ __launch_bounds__(256) void sampler1d_kernel(
    const float4* __restrict__ tex,    // texture as float4 rows: [N_TEX][4]
    const float*  __restrict__ param,  // [U]
    float4*       __restrict__ out)    // [U][4]
{
    const int idx = blockIdx.x * 256 + threadIdx.x;   // 0 .. U*4-1
    const int u = idx >> 2;   // sample index
    const int q = idx & 3;    // which float4 of the 16 channels

    const float p = param[u];
    const float t = p * (float)(N_TEX - 1);
    float f = floorf(t);
    f = fminf(fmaxf(f, 0.0f), (float)(N_TEX - 1));
    const int i0 = (int)f;
    const int i1 = min(i0 + 1, N_TEX - 1);
    const float w  = t - f;
    const float iw = 1.0f - w;

    const float4 a = tex[i0 * 4 + q];
    const float4 b = tex[i1 * 4 + q];

    float4 r;
    r.x = a.x * iw + b.x * w;
    r.y = a.y * iw + b.y * w;
    r.z = a.z * iw + b.z * w;
    r.w = a.w * iw + b.w * w;

    out[idx] = r;
}

extern "C" void kernel_launch(void* const* d_in, const int* in_sizes, int n_in,
                              void* d_out, int out_size, void* d_ws, size_t ws_size,
                              hipStream_t stream) {
    const float4* tex   = (const float4*)d_in[0];  // (N_TEX, C) float32
    const float*  param = (const float*)d_in[1];   // (U,) float32
    float4*       out   = (float4*)d_out;          // (U, C) float32

    const int total_thr = U * 4;                    // 16,777,216
    const int block = 256;
    const int grid  = total_thr / block;            // 65,536 blocks
    sampler1d_kernel<<<grid, block, 0, stream>>>(tex, param, out);
}